// Round 10
// baseline (175.708 us; speedup 1.0000x reference)
//
#include <hip/hip_runtime.h>
#include <math.h>

#define BB 256
#define KK 256
#define VV 256
#define NN 4000
#define MM 4000
#define TOPK 8

// K1: e64 = tanh(qk @ Wk^T + bk); qn64 = e64 / max(||e64||, 1e-8)
// (verbatim from round-2/4 PASSED kernel)
__global__ void k_proj(const float* __restrict__ qk, const float* __restrict__ Wk,
                       const float* __restrict__ bk, double* __restrict__ e64,
                       double* __restrict__ qn64) {
    int b = blockIdx.x, j = threadIdx.x;
    __shared__ float q[KK];
    __shared__ double red[256];
    q[j] = qk[b * KK + j];
    __syncthreads();
    const float* w = Wk + (size_t)j * KK;
    double acc = 0.0;
#pragma unroll 4
    for (int d = 0; d < KK; ++d) acc += (double)q[d] * (double)w[d];
    double val = tanh(acc + (double)bk[j]);
    e64[b * KK + j] = val;
    red[j] = val * val;
    __syncthreads();
    for (int s = 128; s > 0; s >>= 1) {
        if (j < s) red[j] += red[j + s];
        __syncthreads();
    }
    double nrm = fmax(sqrt(red[0]), 1e-8);
    qn64[b * KK + j] = val / nrm;
}

// K2: gather stored_keys = A[midx[m], k, 0]; kn64 = row / max(||row||, 1e-8)
// (verbatim from round-2/4 PASSED kernel)
__global__ void k_kn(const float* __restrict__ A, const int* __restrict__ midx,
                     double* __restrict__ kn64) {
    int m = blockIdx.x, t = threadIdx.x;
    size_t n = (size_t)midx[m];
    double val = (double)A[n * (size_t)(KK * VV) + (size_t)t * VV];
    __shared__ double red[256];
    red[t] = val * val;
    __syncthreads();
    for (int s = 128; s > 0; s >>= 1) {
        if (t < s) red[t] += red[t + s];
        __syncthreads();
    }
    double nrm = fmax(sqrt(red[0]), 1e-8);
    kn64[(size_t)m * KK + t] = val / nrm;
}

// K3 v3b: sims64 = qn64 @ kn64^T, f64. (verbatim from round-9 PASSED kernel)
#define BMS 16
#define BNS 64
#define KS  16
__global__ void __launch_bounds__(64) k_sims(
        const double* __restrict__ qn, const double* __restrict__ kn,
        double* __restrict__ sims) {
    __shared__ double qsT[2][KS][BMS + 2];
    __shared__ double ksT[2][KS][BNS + 8];
    int tid = threadIdx.x;
    int tx = tid & 15, ty = tid >> 4;
    int m0 = blockIdx.x * BNS, b0 = blockIdx.y * BMS;
    int qr = tid & 15;
    int qc = (tid >> 4) * 4;
    int krr = tid >> 3;
    int kc = (tid & 7) * 2;
    const double* qrow = qn + (size_t)(b0 + qr) * KK;
    double acc[4][4] = {};
    int pb = tx * 4 + (tx >> 2) * 2;

    {
        double qreg[4]; double2 kreg[8]; int rr[8];
#pragma unroll
        for (int j = 0; j < 4; ++j) qreg[j] = qrow[qc + j];
#pragma unroll
        for (int s = 0; s < 8; ++s) {
            int r = krr + s * 8; rr[s] = r;
            int mrow = m0 + r;
            const double* kp = kn + (size_t)(mrow < MM ? mrow : 0) * KK + kc;
            kreg[s] = (mrow < MM) ? *(const double2*)kp : make_double2(0.0, 0.0);
        }
#pragma unroll
        for (int j = 0; j < 4; ++j) qsT[0][qc + j][qr] = qreg[j];
#pragma unroll
        for (int s = 0; s < 8; ++s) {
            int p = rr[s] + (rr[s] >> 4) * 2;
            ksT[0][kc][p]     = kreg[s].x;
            ksT[0][kc + 1][p] = kreg[s].y;
        }
    }
    __syncthreads();

    for (int t = 0; t < KK / KS; ++t) {
        int cur = t & 1;
        double qreg[4]; double2 kreg[8]; int rr[8];
        bool have = (t < KK / KS - 1);
        if (have) {
            int kk2 = (t + 1) * KS;
#pragma unroll
            for (int j = 0; j < 4; ++j) qreg[j] = qrow[kk2 + qc + j];
#pragma unroll
            for (int s = 0; s < 8; ++s) {
                int r = krr + s * 8; rr[s] = r;
                int mrow = m0 + r;
                const double* kp = kn + (size_t)(mrow < MM ? mrow : 0) * KK + kk2 + kc;
                kreg[s] = (mrow < MM) ? *(const double2*)kp : make_double2(0.0, 0.0);
            }
        }
#pragma unroll
        for (int i = 0; i < KS; ++i) {
            double qv[4], kv[4];
            *(double2*)&qv[0] = *(const double2*)&qsT[cur][i][ty * 4];
            *(double2*)&qv[2] = *(const double2*)&qsT[cur][i][ty * 4 + 2];
            *(double2*)&kv[0] = *(const double2*)&ksT[cur][i][pb];
            *(double2*)&kv[2] = *(const double2*)&ksT[cur][i][pb + 2];
#pragma unroll
            for (int a = 0; a < 4; ++a)
#pragma unroll
                for (int c = 0; c < 4; ++c)
                    acc[a][c] += qv[a] * kv[c];
        }
        if (have) {
            int nxt = cur ^ 1;
#pragma unroll
            for (int j = 0; j < 4; ++j) qsT[nxt][qc + j][qr] = qreg[j];
#pragma unroll
            for (int s = 0; s < 8; ++s) {
                int p = rr[s] + (rr[s] >> 4) * 2;
                ksT[nxt][kc][p]     = kreg[s].x;
                ksT[nxt][kc + 1][p] = kreg[s].y;
            }
        }
        __syncthreads();
    }
#pragma unroll
    for (int a = 0; a < 4; ++a) {
        int bb = b0 + ty * 4 + a;
#pragma unroll
        for (int c = 0; c < 4; ++c) {
            int mm2 = m0 + tx * 4 + c;
            if (mm2 < MM) sims[(size_t)bb * MM + mm2] = acc[a][c];
        }
    }
}

// K4: per-row top-8 (value desc, stable by index) in f64 + confidences
// (verbatim from round-2 PASSED kernel)
__global__ void k_topk(const double* __restrict__ sims, const int* __restrict__ midx,
                       const float* __restrict__ usage, float* __restrict__ out_conf,
                       float* __restrict__ out_sims, int* __restrict__ acts) {
    int b = blockIdx.x, t = threadIdx.x;
    double v[TOPK];
    int id[TOPK];
#pragma unroll
    for (int i = 0; i < TOPK; ++i) { v[i] = -INFINITY; id[i] = 0x7fffffff; }
    const double* row = sims + (size_t)b * MM;
    for (int m = t; m < MM; m += 256) {
        double x = row[m];
        if (x > v[TOPK - 1]) {
            v[TOPK - 1] = x; id[TOPK - 1] = m;
#pragma unroll
            for (int i = TOPK - 1; i > 0; --i) {
                if (v[i] > v[i - 1]) {  // strict: equal values keep smaller index first
                    double tv = v[i]; v[i] = v[i - 1]; v[i - 1] = tv;
                    int ti = id[i]; id[i] = id[i - 1]; id[i - 1] = ti;
                }
            }
        }
    }
    __shared__ double sv[256 * TOPK];
    __shared__ int si[256 * TOPK];
#pragma unroll
    for (int i = 0; i < TOPK; ++i) { sv[t * TOPK + i] = v[i]; si[t * TOPK + i] = id[i]; }
    __syncthreads();
    for (int stride = 128; stride > 0; stride >>= 1) {
        if (t < stride) {
            double* av = &sv[t * TOPK];
            int*    ai = &si[t * TOPK];
            double* bv = &sv[(t + stride) * TOPK];
            int*    bi = &si[(t + stride) * TOPK];
            double mv[TOPK]; int mi[TOPK];
            int pa = 0, pb = 0;
#pragma unroll
            for (int i = 0; i < TOPK; ++i) {
                double va = av[pa], vb = bv[pb];
                bool takeA = (va > vb) || (va == vb && ai[pa] < bi[pb]);
                if (takeA) { mv[i] = va; mi[i] = ai[pa]; ++pa; }
                else       { mv[i] = vb; mi[i] = bi[pb]; ++pb; }
            }
#pragma unroll
            for (int i = 0; i < TOPK; ++i) { av[i] = mv[i]; ai[i] = mi[i]; }
        }
        __syncthreads();
    }
    if (t < TOPK) {
        double val = sv[t];
        int idx = si[t];
        int actual = midx[idx];
        out_sims[b * TOPK + t] = (float)val;
        out_conf[b * TOPK + t] = (float)(val * (1.0 + log1p((double)usage[actual])));
        acts[b * TOPK + t] = actual;
    }
}

// K4b: owner table for dedup. own[n] = min slot index with acts[slot]==n.
// Init is independent of acts (launched early, off the critical path).
__global__ void __launch_bounds__(256) k_own_init(int* __restrict__ own) {
    int i = blockIdx.x * 256 + threadIdx.x;
    if (i < NN) own[i] = 0x7fffffff;
}
__global__ void __launch_bounds__(256) k_own_min(const int* __restrict__ acts,
                                                 int* __restrict__ own) {
    int i = blockIdx.x * 256 + threadIdx.x;   // i in [0, 2048)
    atomicMin(&own[acts[i]], i);
}

// K5: dedup'd retrieval. Owner block (min slot for its n) computes outputs for
// ALL slots sharing that A-row, in chunks of 2; chunk >=2 re-streams A[n] from
// its own L2 (256KB << 4MB). Per-slot arithmetic (float4 loads, fmaf order,
// 4-wave part-reduce) is verbatim r9 => outputs bit-identical. Non-owner
// blocks exit immediately. List order via LDS atomicAdd is nondeterministic,
// but each slot's output depends only on its own (b, n) => deterministic out.
__global__ void __launch_bounds__(256) k_retr(
        const float* __restrict__ A, const double* __restrict__ e64,
        const int* __restrict__ acts, const int* __restrict__ own,
        float* __restrict__ out) {
    int bk_ = blockIdx.x;
    int n_i = acts[bk_];
    if (own[n_i] != bk_) return;           // uniform branch

    __shared__ int list[BB * TOPK];
    __shared__ int cnt_s;
    __shared__ float es[2][KK];
    __shared__ float part[2][4][64][4];
    int tid = threadIdx.x;
    if (tid == 0) cnt_s = 0;
    __syncthreads();
    for (int j = tid; j < BB * TOPK; j += 256)
        if (acts[j] == n_i) list[atomicAdd(&cnt_s, 1)] = j;
    __syncthreads();
    int cn = cnt_s;

    int w = tid >> 6, l = tid & 63;
    const float* base = A + (size_t)n_i * (KK * VV) + (size_t)(w * 64) * VV + 4 * l;

    for (int c0 = 0; c0 < cn; c0 += 2) {
        int s0 = list[c0];
        int s1 = (c0 + 1 < cn) ? list[c0 + 1] : -1;
        es[0][tid] = (float)e64[(s0 >> 3) * KK + tid];
        es[1][tid] = (s1 >= 0) ? (float)e64[(s1 >> 3) * KK + tid] : 0.f;
        __syncthreads();
        float ax0 = 0.f, ay0 = 0.f, az0 = 0.f, aw0 = 0.f;
        float ax1 = 0.f, ay1 = 0.f, az1 = 0.f, aw1 = 0.f;
#pragma unroll 8
        for (int dd = 0; dd < 64; ++dd) {
            const float4 a = *reinterpret_cast<const float4*>(base + (size_t)dd * VV);
            float e0 = es[0][w * 64 + dd];
            ax0 = fmaf(e0, a.x, ax0); ay0 = fmaf(e0, a.y, ay0);
            az0 = fmaf(e0, a.z, az0); aw0 = fmaf(e0, a.w, aw0);
            float e1 = es[1][w * 64 + dd];
            ax1 = fmaf(e1, a.x, ax1); ay1 = fmaf(e1, a.y, ay1);
            az1 = fmaf(e1, a.z, az1); aw1 = fmaf(e1, a.w, aw1);
        }
        part[0][w][l][0] = ax0; part[0][w][l][1] = ay0;
        part[0][w][l][2] = az0; part[0][w][l][3] = aw0;
        part[1][w][l][0] = ax1; part[1][w][l][1] = ay1;
        part[1][w][l][2] = az1; part[1][w][l][3] = aw1;
        __syncthreads();
        int l2 = tid >> 2, j = tid & 3;
        float r0 = part[0][0][l2][j] + part[0][1][l2][j]
                 + part[0][2][l2][j] + part[0][3][l2][j];
        out[(size_t)s0 * VV + tid] = r0;
        if (s1 >= 0) {
            float r1 = part[1][0][l2][j] + part[1][1][l2][j]
                     + part[1][2][l2][j] + part[1][3][l2][j];
            out[(size_t)s1 * VV + tid] = r1;
        }
        __syncthreads();   // es/part reused next chunk
    }
}

extern "C" void kernel_launch(void* const* d_in, const int* in_sizes, int n_in,
                              void* d_out, int out_size, void* d_ws, size_t ws_size,
                              hipStream_t stream) {
    const float* qk    = (const float*)d_in[0];
    const float* Wk    = (const float*)d_in[1];
    const float* bk    = (const float*)d_in[2];
    const float* A     = (const float*)d_in[3];
    const float* usage = (const float*)d_in[4];
    const int*   midx  = (const int*)d_in[5];

    float* out   = (float*)d_out;
    float* retr  = out;                                 // B*TOPK*V = 524288
    float* conf  = out + (size_t)BB * TOPK * VV;        // 2048
    float* tsims = conf + BB * TOPK;                    // 2048

    // workspace layout: r2/r4/r9 PASSED layout + own[] table at the end
    double* ws64  = (double*)d_ws;
    double* e64   = ws64;                               // 65536 doubles
    double* qn64  = e64 + BB * KK;                      // 65536
    double* kn64  = qn64 + BB * KK;                     // 1,024,000
    double* sims  = kn64 + (size_t)MM * KK;             // 1,024,000
    int*    acts  = (int*)(sims + (size_t)BB * MM);     // 2048 ints
    int*    own   = acts + BB * TOPK;                   // 4000 ints

    k_proj<<<BB, 256, 0, stream>>>(qk, Wk, bk, e64, qn64);
    k_kn<<<MM, 256, 0, stream>>>(A, midx, kn64);
    k_own_init<<<(NN + 255) / 256, 256, 0, stream>>>(own);   // off critical path
    dim3 g3((MM + BNS - 1) / BNS, BB / BMS);            // 63 x 16 = 1008 blocks
    k_sims<<<g3, 64, 0, stream>>>(qn64, kn64, sims);
    k_topk<<<BB, 256, 0, stream>>>(sims, midx, usage, conf, tsims, acts);
    k_own_min<<<(BB * TOPK) / 256, 256, 0, stream>>>(acts, own);
    k_retr<<<BB * TOPK, 256, 0, stream>>>(A, e64, acts, own, retr);
}